// Round 2
// baseline (753.532 us; speedup 1.0000x reference)
//
#include <hip/hip_runtime.h>

// Zero-phase FIR band-pass via bf16 MFMA (banded-Toeplitz formulation).
//
// out[t] = sum_{j=0}^{412} h[j] * xs(t + 206 - j)
// xs(s) = x[s] in range; 2*x[0]-x[-s] left; 2*x[T-1]-x[2T-2-s] right.
//
// MFMA mapping (16x16x32 bf16, D[r][n], t = tb + 16n + r):
//   A_sig[r][k] = h[430 + r - k - 32*sig]   (0 if index outside [0,412]),  sig in [0,14)
//   B_sig[k][n] = xs(tb - 224 + 32*sig + k + 16n)
//   out = sum_sig A_sig * B_sig    (each tap j hits exactly one sig)
//
// R2: ZERO-BARRIER design. Persistent per-signal blocks; each wave stages its
//     own private 928-sample window (116 chunks, double-buffered) and computes
//     its own 512 outputs per tile. No __syncthreads in the main loop: within a
//     wave the DS queue is in-order and lgkmcnt ordering suffices. Waves drift
//     freely -> the ~16 resident waves/CU hide each other's LDS/MFMA/global
//     latency instead of lockstepping on 2 barriers per tile (the R0/R1 limiter:
//     ~11k cyc wall per block-tile vs ~1.4k cyc of actual pipe work).

#define T_LEN   30000
#define NTAPS   413
#define BLOCK   256            // 4 waves
#define OUT_BLK 2048           // outputs per block-iteration (4 waves x 512)
#define W_OUT   512            // outputs per wave-tile (2 MFMA sub-tiles of 256)
#define BLK_PER_SIG 15         // ceil(30000/2048)
#define NSIG_A  14             // sigma count (448 effective taps >= 413+15)
#define W_CHUNKS 116           // staged 16B chunks per wave-tile (928 samples)
#define W_PAD   132            // cpad(115)=129 -> 130 needed; rounded up

typedef __bf16 bf16x8 __attribute__((ext_vector_type(8)));
typedef float  f32x4  __attribute__((ext_vector_type(4)));

union Chunk {
    uint4 v;
    unsigned short us[8];
    bf16x8 f;
};

__device__ __forceinline__ unsigned short f32_to_bf16_rne(float f) {
    unsigned u = __float_as_uint(f);
    unsigned r = u + 0x7FFFu + ((u >> 16) & 1u);
    return (unsigned short)(r >> 16);
}

// phys index of logical 16B chunk u (pad 1 chunk per 8 -> breaks even-stride conflicts)
__device__ __forceinline__ int cpad(int u) { return u + (u >> 3); }

__global__ void prep_A_kernel(const float* __restrict__ h, uint4* __restrict__ wsA) {
    int i = blockIdx.x * blockDim.x + threadIdx.x;   // 0 .. 14*64-1
    if (i >= NSIG_A * 64) return;
    int sig = i >> 6, lane = i & 63;
    int r = lane & 15, q = lane >> 4;
    Chunk c;
    #pragma unroll
    for (int j = 0; j < 8; ++j) {
        int idx = 430 + r - 8 * q - j - 32 * sig;
        float v = (idx >= 0 && idx < NTAPS) ? h[idx] : 0.0f;
        c.us[j] = f32_to_bf16_rne(v);
    }
    wsA[i] = c.v;
}

// raw (unconverted) load of the 8 floats feeding chunk with first index g0
__device__ __forceinline__ void chunk_load(const float* __restrict__ xp, int g0,
                                           float r[8]) {
    if (g0 >= 0 && g0 + 8 <= T_LEN) {
        float4 a = *reinterpret_cast<const float4*>(xp + g0);
        float4 b = *reinterpret_cast<const float4*>(xp + g0 + 4);
        r[0] = a.x; r[1] = a.y; r[2] = a.z; r[3] = a.w;
        r[4] = b.x; r[5] = b.y; r[6] = b.z; r[7] = b.w;
    } else {
        #pragma unroll
        for (int j = 0; j < 8; ++j) {
            int g = g0 + j;
            int idx = (g < 0) ? -g : ((g >= T_LEN) ? (2 * T_LEN - 2 - g) : g);
            r[j] = xp[idx];
        }
    }
}

// convert (+reflect fixup on edge chunks) and write chunk u into an LDS buffer
__device__ __forceinline__ void chunk_store(uint4* __restrict__ buf, int u, int g0,
                                            const float r[8], float x0, float xl) {
    Chunk c;
    if (g0 >= 0 && g0 + 8 <= T_LEN) {
        #pragma unroll
        for (int j = 0; j < 8; ++j) c.us[j] = f32_to_bf16_rne(r[j]);
    } else {
        #pragma unroll
        for (int j = 0; j < 8; ++j) {
            int g = g0 + j;
            float v = r[j];
            if (g < 0)           v = 2.0f * x0 - v;
            else if (g >= T_LEN) v = 2.0f * xl - v;
            c.us[j] = f32_to_bf16_rne(v);
        }
    }
    buf[cpad(u)] = c.v;
}

__global__ __launch_bounds__(BLOCK, 4) void fir_mfma_kernel(
    const float* __restrict__ x, const uint4* __restrict__ wsA,
    float* __restrict__ out)
{
    // per-wave private double-buffered staging: lds[wave][buf][chunk]
    __shared__ uint4 lds[4][2][W_PAD];

    const int tid  = threadIdx.x;
    const int lane = tid & 63;
    const int wv   = tid >> 6;
    const int sig_id = blockIdx.x;
    const float* xp = x   + (size_t)sig_id * T_LEN;
    float*       op = out + (size_t)sig_id * T_LEN;

    // ---- load A fragments once per signal (L2-hot after first blocks) ----
    bf16x8 A[NSIG_A];
    #pragma unroll
    for (int s = 0; s < NSIG_A; ++s) {
        Chunk c; c.v = wsA[s * 64 + lane];
        A[s] = c.f;
    }

    const float x0 = xp[0], xl = xp[T_LEN - 1];

    // each lane owns chunk `lane`, plus chunk 64+lane for lane < 52
    const bool has2 = (lane < W_CHUNKS - 64);
    float r0[8], r1[8];

    // ---- prologue: stage this wave's tile 0 window ----
    {
        const int g0 = wv * W_OUT - 224 + 8 * lane;
        chunk_load(xp, g0, r0);
        if (has2) chunk_load(xp, g0 + 512, r1);
        chunk_store(&lds[wv][0][0], lane, g0, r0, x0, xl);
        if (has2) chunk_store(&lds[wv][0][0], 64 + lane, g0 + 512, r1, x0, xl);
    }

    const int n = lane & 15, q = lane >> 4;
    const int base_u = 2 * n + q;

    for (int blk = 0; blk < BLK_PER_SIG; ++blk) {
        const int cur = blk & 1;
        const int tw0 = blk * OUT_BLK + wv * W_OUT;   // this wave-tile's first output
        const bool pf = (blk + 1 < BLK_PER_SIG);
        const int ng0 = tw0 + OUT_BLK - 224 + 8 * lane;

        // ---- issue next tile's global loads (in flight across the compute) ----
        if (pf) {
            chunk_load(xp, ng0, r0);
            if (has2) chunk_load(xp, ng0 + 512, r1);
        }

        // ---- compute: sub-tiles mt=0,1; fragments shared along phi ----
        const uint4* __restrict__ cb = &lds[wv][cur][0];
        f32x4 acc0 = {0.f, 0.f, 0.f, 0.f};
        f32x4 acc1 = {0.f, 0.f, 0.f, 0.f};
        #pragma unroll
        for (int phi = 0; phi < NSIG_A + 8; ++phi) {   // 22
            Chunk c; c.v = cb[cpad(base_u + 4 * phi)];
            bf16x8 B = c.f;
            if (phi < NSIG_A)
                acc0 = __builtin_amdgcn_mfma_f32_16x16x32_bf16(A[phi], B, acc0, 0, 0, 0);
            if (phi >= 8)
                acc1 = __builtin_amdgcn_mfma_f32_16x16x32_bf16(A[phi - 8], B, acc1, 0, 0, 0);
        }

        // ---- store: C/D layout col=lane&15 (n), row=(lane>>4)*4+v.
        // t = tw0 + 256*mt + 16n + 4q + v -> one float4 per lane, coalesced. ----
        const int tA = tw0 + 16 * n + 4 * q;
        if (tA < T_LEN)
            *reinterpret_cast<float4*>(op + tA) =
                make_float4(acc0.x, acc0.y, acc0.z, acc0.w);
        const int tB = tA + 256;
        if (tB < T_LEN)
            *reinterpret_cast<float4*>(op + tB) =
                make_float4(acc1.x, acc1.y, acc1.z, acc1.w);

        // ---- convert + write next tile into the other private buffer.
        // No barrier: in-order per-wave DS queue + compiler lgkmcnt ordering
        // guarantee read-before-overwrite and write-before-next-read. ----
        if (pf) {
            uint4* __restrict__ nb = &lds[wv][cur ^ 1][0];
            chunk_store(nb, lane, ng0, r0, x0, xl);
            if (has2) chunk_store(nb, 64 + lane, ng0 + 512, r1, x0, xl);
        }
    }
}

extern "C" void kernel_launch(void* const* d_in, const int* in_sizes, int n_in,
                              void* d_out, int out_size, void* d_ws, size_t ws_size,
                              hipStream_t stream) {
    const float* x = (const float*)d_in[0];
    const float* h = (const float*)d_in[1];
    float* out = (float*)d_out;
    uint4* wsA = (uint4*)d_ws;                       // 14*64*16 = 14336 B
    const int nsig = in_sizes[0] / T_LEN;            // 2048

    prep_A_kernel<<<dim3(4), dim3(BLOCK), 0, stream>>>(h, wsA);
    fir_mfma_kernel<<<dim3(nsig), dim3(BLOCK), 0, stream>>>(x, wsA, out);
}

// Round 4
// 488.545 us; speedup vs baseline: 1.5424x; 1.5424x over previous
//
#include <hip/hip_runtime.h>

// Zero-phase FIR band-pass via bf16 MFMA (banded-Toeplitz formulation).
//
// out[t] = sum_{j=0}^{412} h[j] * xs(t + 206 - j)
// xs(s) = x[s] in range; 2*x[0]-x[-s] left; 2*x[T-1]-x[2T-2-s] right.
//
// R3 (resubmit R4: container infra failure, no counters): 32x32x16 MFMA mapping.
// Per wave-tile of 1024 outputs:
//   A_sig[r][k] = h[414 + r - k - 16*sig]  (0 outside [0,413)), sig in [0,28)
//   B_sig[k][c] = xs(tb + 32c + k + 16*sig - 208)
//   D[r][c] = out[tb + 32c + r] = sum_sig A_sig*B_sig   (each tap exactly once:
//   j = 414+r-k-16sig covers [0,413) bijectively for every r in [0,32)).
// 28 ds_read_b128 + 28 MFMA per 1024 outputs (vs 44+56 for 16x16x32).
// C/D layout: col=lane&31, row=(reg&3)+8*(reg>>2)+4*(lane>>5)  [m74/m101].
// A/B layout: lane = 32*kgrp + row/col, elements k = 8*kgrp..8*kgrp+7 (same
// family as the verified 16x16x32 mapping).
//
// Structure: block-cooperative barrier-synced staging (the R0/R1-proven shape;
// R2's wave-private no-barrier staging exploded HBM fetch 9x and regressed 3x).
// Persistent per-signal blocks, 8 tiles of 4096 outputs (last tile re-anchored
// at t0=25904 -> no wasted compute, no OOB; overlap region rewritten with
// identical values by construction).
// LDS padding cpad2(u)=u+(u>>2): conflict-free for the 32x32 read pattern
// (u = 128wv + 4c + b + 2sig) and for linear staging writes.

#define T_LEN   30000
#define NTAPS   413
#define BLOCK   256            // 4 waves
#define OUT_BLK 4096           // outputs per block-tile (4 waves x 1024)
#define NTILE   8              // 7 x 4096 + re-anchored last tile
#define LAST_T0 25904          // 30000 - 4096
#define NSIG    28             // sigma count: 16*28 = 448 >= 413 + 32 + pad
#define NCHUNK3 564            // staged 16B chunks per block-tile (4512 samples)
#define LDS_PHYS 704           // cpad2(563) = 703 -> 704

typedef __bf16 bf16x8 __attribute__((ext_vector_type(8)));
typedef float  f32x16 __attribute__((ext_vector_type(16)));

union Chunk {
    uint4 v;
    unsigned short us[8];
    bf16x8 f;
};

__device__ __forceinline__ unsigned short f32_to_bf16_rne(float f) {
    unsigned u = __float_as_uint(f);
    unsigned r = u + 0x7FFFu + ((u >> 16) & 1u);
    return (unsigned short)(r >> 16);
}

// phys index of logical 16B chunk u: 1 pad chunk per 4 -> conflict-free for
// both the staging writes (lane-linear) and compute reads (u = base + 4c + b).
__device__ __forceinline__ int cpad2(int u) { return u + (u >> 2); }

__global__ void prep_A_kernel(const float* __restrict__ h, uint4* __restrict__ wsA) {
    int i = blockIdx.x * blockDim.x + threadIdx.x;   // 0 .. 28*64-1
    if (i >= NSIG * 64) return;
    int sig = i >> 6, lane = i & 63;
    int r = lane & 31, b = lane >> 5;
    Chunk c;
    #pragma unroll
    for (int j = 0; j < 8; ++j) {
        int idx = 414 + r - 8 * b - j - 16 * sig;
        float v = (idx >= 0 && idx < NTAPS) ? h[idx] : 0.0f;
        c.us[j] = f32_to_bf16_rne(v);
    }
    wsA[i] = c.v;
}

// stage chunk u (samples s0+8u .. s0+8u+7, reflect-extended) into LDS
__device__ __forceinline__ void stage_chunk(uint4* __restrict__ buf,
                                            const float* __restrict__ xp,
                                            int u, int s0) {
    int g0 = s0 + 8 * u;
    Chunk c;
    if (g0 >= 0 && g0 + 8 <= T_LEN) {
        float4 a = *reinterpret_cast<const float4*>(xp + g0);
        float4 b = *reinterpret_cast<const float4*>(xp + g0 + 4);
        c.us[0] = f32_to_bf16_rne(a.x); c.us[1] = f32_to_bf16_rne(a.y);
        c.us[2] = f32_to_bf16_rne(a.z); c.us[3] = f32_to_bf16_rne(a.w);
        c.us[4] = f32_to_bf16_rne(b.x); c.us[5] = f32_to_bf16_rne(b.y);
        c.us[6] = f32_to_bf16_rne(b.z); c.us[7] = f32_to_bf16_rne(b.w);
    } else {
        float x0 = xp[0], xl = xp[T_LEN - 1];
        #pragma unroll
        for (int j = 0; j < 8; ++j) {
            int g = g0 + j;
            float v;
            if (g < 0)            v = 2.0f * x0 - xp[-g];
            else if (g >= T_LEN)  v = 2.0f * xl - xp[2 * T_LEN - 2 - g];
            else                  v = xp[g];
            c.us[j] = f32_to_bf16_rne(v);
        }
    }
    buf[cpad2(u)] = c.v;
}

__global__ __launch_bounds__(BLOCK, 3) void fir_mfma_kernel(
    const float* __restrict__ x, const uint4* __restrict__ wsA,
    float* __restrict__ out)
{
    __shared__ uint4 lds[LDS_PHYS];     // 11264 B

    const int tid  = threadIdx.x;
    const int lane = tid & 63;
    const int wv   = tid >> 6;
    const int sig_id = blockIdx.x;
    const float* xp = x   + (size_t)sig_id * T_LEN;
    float*       op = out + (size_t)sig_id * T_LEN;

    // ---- load A fragments once per signal (28 x 16B/lane, L2-hot) ----
    bf16x8 A[NSIG];
    #pragma unroll
    for (int s = 0; s < NSIG; ++s) {
        Chunk c; c.v = wsA[s * 64 + lane];
        A[s] = c.f;
    }

    const int c31 = lane & 31;          // output column within 32x32 tile
    const int kb  = lane >> 5;          // k-group (b)
    const int ub  = 128 * wv + 4 * c31 + kb;   // B chunk base for this lane

    for (int blk = 0; blk < NTILE; ++blk) {
        const int t0 = (blk < NTILE - 1) ? blk * OUT_BLK : LAST_T0;
        const int s0 = t0 - 208;        // chunk 0 = sample s0 (8- and 4-aligned)

        // ---- cooperative staging: 564 chunks over 256 threads ----
        stage_chunk(lds, xp, tid, s0);
        stage_chunk(lds, xp, tid + 256, s0);
        if (tid < NCHUNK3 - 512) stage_chunk(lds, xp, tid + 512, s0);
        __syncthreads();

        // ---- compute: one 32x32 tile per wave, 28 sigma steps ----
        f32x16 acc = {0.f, 0.f, 0.f, 0.f, 0.f, 0.f, 0.f, 0.f,
                      0.f, 0.f, 0.f, 0.f, 0.f, 0.f, 0.f, 0.f};
        #pragma unroll
        for (int sg = 0; sg < NSIG; ++sg) {
            Chunk ch; ch.v = lds[cpad2(ub + 2 * sg)];
            acc = __builtin_amdgcn_mfma_f32_32x32x16_bf16(A[sg], ch.f, acc, 0, 0, 0);
        }

        // ---- store: t = tb + 32*c31 + row, row = (reg&3) + 8*(reg>>2) + 4*kb.
        // float4 group g covers rows 8g+4kb+0..3 -> contiguous 16B per lane.
        // Wave covers all 32 128B-lines of the 4KB tile across the 4 stores
        // (32B sectors per instruction -> sector-aligned, no RMW expected). ----
        const int tb   = t0 + 1024 * wv;
        const int tcol = tb + 32 * c31 + 4 * kb;   // max 29999 by construction
        #pragma unroll
        for (int g = 0; g < 4; ++g) {
            *reinterpret_cast<float4*>(op + tcol + 8 * g) =
                make_float4(acc[4 * g + 0], acc[4 * g + 1],
                            acc[4 * g + 2], acc[4 * g + 3]);
        }
        __syncthreads();   // protect LDS before next tile's staging
    }
}

extern "C" void kernel_launch(void* const* d_in, const int* in_sizes, int n_in,
                              void* d_out, int out_size, void* d_ws, size_t ws_size,
                              hipStream_t stream) {
    const float* x = (const float*)d_in[0];
    const float* h = (const float*)d_in[1];
    float* out = (float*)d_out;
    uint4* wsA = (uint4*)d_ws;                       // 28*64*16 = 28672 B
    const int nsig = in_sizes[0] / T_LEN;            // 2048

    prep_A_kernel<<<dim3(7), dim3(BLOCK), 0, stream>>>(h, wsA);
    fir_mfma_kernel<<<dim3(nsig), dim3(BLOCK), 0, stream>>>(x, wsA, out);
}